// Round 10
// baseline (249.159 us; speedup 1.0000x reference)
//
#include <hip/hip_runtime.h>
#include <stdint.h>

#define L_SEQ   2048
#define DM      1024
#define NH      16
#define DK      64
#define BATCH   4
#define M_TOK   (BATCH * L_SEQ)   // 8192

typedef __attribute__((ext_vector_type(8))) short bf16x8;
typedef __attribute__((ext_vector_type(4))) float f32x4;
typedef __attribute__((ext_vector_type(16))) float f32x16;
typedef __attribute__((ext_vector_type(4))) unsigned int u32x4;

typedef __attribute__((address_space(1))) void void_g;
typedef __attribute__((address_space(3))) void void_l;

#define EXP2F(x) __builtin_amdgcn_exp2f(x)

__device__ __forceinline__ unsigned short f2bf(float f) {
  unsigned int u = __builtin_bit_cast(unsigned int, f);
  u += 0x7FFFu + ((u >> 16) & 1u);
  return (unsigned short)(u >> 16);
}

// ---------------- fp32 -> bf16 converts ----------------
__global__ void cvt_f32_bf16(const float* __restrict__ src,
                             unsigned short* __restrict__ dst, int n4) {
  int i = blockIdx.x * blockDim.x + threadIdx.x;
  int stride = gridDim.x * blockDim.x;
  for (; i < n4; i += stride) {
    float4 v = ((const float4*)src)[i];
    ushort4 o;
    o.x = f2bf(v.x); o.y = f2bf(v.y); o.z = f2bf(v.z); o.w = f2bf(v.w);
    ((ushort4*)dst)[i] = o;
  }
}

// 4 weight matrices (1024x1024 each) -> contiguous bf16 dst, one launch
__global__ void cvt_w4(const float* __restrict__ s0, const float* __restrict__ s1,
                       const float* __restrict__ s2, const float* __restrict__ s3,
                       unsigned short* __restrict__ dst) {
  int i = blockIdx.x * blockDim.x + threadIdx.x;      // 0 .. 4*262144-1
  int sel = i >> 18, j = i & 0x3FFFF;
  const float* s = sel == 0 ? s0 : sel == 1 ? s1 : sel == 2 ? s2 : s3;
  float4 v = ((const float4*)s)[j];
  ushort4 o;
  o.x = f2bf(v.x); o.y = f2bf(v.y); o.z = f2bf(v.z); o.w = f2bf(v.w);
  ((ushort4*)(dst + (size_t)sel * DM * DM))[j] = o;
}

// ---------------- deep-pipelined GEMM, 2-phase/K-tile (T2+T3+T4+T5) -------
// (unchanged from R9 — frozen this round for attribution)
#define GBM 128
#define GBN 256
#define GBK 64
#define NKT (DM / GBK)            // 16 K-tiles
#define ATILE (GBM * GBK)         // 8192 elems
#define BTILE (GBN * GBK)         // 16384 elems
#define BUFE (ATILE + BTILE)      // 24576 elems per buffer

__device__ __forceinline__ void stage_A(
    const unsigned short* __restrict__ A, unsigned short* buf,
    int tm, int k0, int t) {
  const int l = t & 63, w = t >> 6;
  const int su = (l & 7) ^ (l >> 3);          // pre-swizzled source unit
  const int rw = w * 8 + (l >> 3);
  const unsigned short* asrc = A + (size_t)(tm + rw) * DM + k0 + su * 8;
#pragma unroll
  for (int r = 0; r < 2; ++r)                 // A: 128 rows = 2 rounds
    __builtin_amdgcn_global_load_lds(
        (const void_g*)(asrc + (size_t)r * 64 * DM),
        (void_l*)(buf + r * 4096 + w * 512), 16, 0, 0);
}

__device__ __forceinline__ void stage_B(
    const unsigned short* __restrict__ Bw, unsigned short* buf,
    int tn, int k0, int t) {
  const int l = t & 63, w = t >> 6;
  const int su = (l & 7) ^ (l >> 3);
  const int rw = w * 8 + (l >> 3);
  const unsigned short* bsrc = Bw + (size_t)(tn + rw) * DM + k0 + su * 8;
#pragma unroll
  for (int r = 0; r < 4; ++r)                 // B: 256 rows = 4 rounds
    __builtin_amdgcn_global_load_lds(
        (const void_g*)(bsrc + (size_t)r * 64 * DM),
        (void_l*)(buf + ATILE + r * 4096 + w * 512), 16, 0, 0);
}

__device__ __forceinline__ bf16x8 frag_ld(const unsigned short* base, int R, int u) {
  return *(const bf16x8*)(base + R * 64 + (u ^ (R & 7)) * 8);
}

// EPI 0: QKV-split epilogue (bf16, head layouts). EPI 1: fp32 out + bias.
template <int EPI>
__global__ __launch_bounds__(512, 2) void gemm8(
    const unsigned short* __restrict__ A,
    const unsigned short* __restrict__ Bw,
    const float* __restrict__ b0, const float* __restrict__ b1,
    const float* __restrict__ b2, float qscale,
    void* __restrict__ out) {
  __shared__ unsigned short L[3 * BUFE];      // 147456 B

  const int tidx = threadIdx.x;
  const int wid = tidx >> 6, lane = tidx & 63;
  const int wm = wid >> 2, wn = wid & 3;      // 2M x 4N
  const int lr = lane & 15, lg4 = lane >> 4;

  // bijective XCD swizzle (nwg % 8 == 0 for both grids)
  int wg = blockIdx.y * gridDim.x + blockIdx.x;
  int nwg = gridDim.x * gridDim.y;
  int swz = (wg & 7) * (nwg >> 3) + (wg >> 3);
  const int tm = (swz / gridDim.x) * GBM, tn = (swz % gridDim.x) * GBN;

  f32x4 acc[4][4];
#pragma unroll
  for (int m = 0; m < 4; ++m)
#pragma unroll
    for (int n = 0; n < 4; ++n) acc[m][n] = (f32x4)0.0f;

  // prologue: 2 tiles in flight (6 loads/thread each)
  stage_A(A, L, tm, 0, tidx);
  stage_B(Bw, L, tn, 0, tidx);
  stage_A(A, L + BUFE, tm, GBK, tidx);
  stage_B(Bw, L + BUFE, tn, GBK, tidx);
  asm volatile("s_waitcnt vmcnt(6)" ::: "memory");   // tile0 landed
  __builtin_amdgcn_s_barrier();

  for (int i = 0; i < NKT; ++i) {
    unsigned short* cb = L + (i % 3) * BUFE;
    unsigned short* nb = L + ((i + 2) % 3) * BUFE;
    const bool pf = (i + 2 < NKT);
    const int kn = (i + 2) * GBK;

    // ---- phase A (kk=0): ds-load subtile || stage-A issue -> MFMA cluster
    bf16x8 a0[4], bv0[4];
#pragma unroll
    for (int m = 0; m < 4; ++m)
      a0[m] = frag_ld(cb, wm * 64 + m * 16 + lr, lg4);
#pragma unroll
    for (int n = 0; n < 4; ++n)
      bv0[n] = frag_ld(cb + ATILE, wn * 64 + n * 16 + lr, lg4);
    if (pf) stage_A(A, nb, tm, kn, tidx);
    __builtin_amdgcn_s_barrier();
    asm volatile("s_waitcnt lgkmcnt(0)" ::: "memory");
    __builtin_amdgcn_s_setprio(1);
#pragma unroll
    for (int m = 0; m < 4; ++m)
#pragma unroll
      for (int n = 0; n < 4; ++n)
        acc[m][n] = __builtin_amdgcn_mfma_f32_16x16x32_bf16(a0[m], bv0[n], acc[m][n], 0, 0, 0);
    __builtin_amdgcn_s_setprio(0);
    __builtin_amdgcn_s_barrier();

    // ---- phase B (kk=1): ds-load subtile || stage-B issue -> vmcnt -> MFMA
    bf16x8 a1[4], bv1[4];
#pragma unroll
    for (int m = 0; m < 4; ++m)
      a1[m] = frag_ld(cb, wm * 64 + m * 16 + lr, 4 + lg4);
#pragma unroll
    for (int n = 0; n < 4; ++n)
      bv1[n] = frag_ld(cb + ATILE, wn * 64 + n * 16 + lr, 4 + lg4);
    if (pf) {
      stage_B(Bw, nb, tn, kn, tidx);
      asm volatile("s_waitcnt vmcnt(6)" ::: "memory");   // tile i+1 landed
    } else {
      asm volatile("s_waitcnt vmcnt(0)" ::: "memory");   // drain tail
    }
    __builtin_amdgcn_s_barrier();
    asm volatile("s_waitcnt lgkmcnt(0)" ::: "memory");
    __builtin_amdgcn_s_setprio(1);
#pragma unroll
    for (int m = 0; m < 4; ++m)
#pragma unroll
      for (int n = 0; n < 4; ++n)
        acc[m][n] = __builtin_amdgcn_mfma_f32_16x16x32_bf16(a1[m], bv1[n], acc[m][n], 0, 0, 0);
    __builtin_amdgcn_s_setprio(0);
    __builtin_amdgcn_s_barrier();
  }

  // epilogue
  if (EPI == 1) {
    float* o = (float*)out;
#pragma unroll
    for (int m = 0; m < 4; ++m) {
      int row0 = tm + wm * 64 + m * 16 + lg4 * 4;
#pragma unroll
      for (int n = 0; n < 4; ++n) {
        int col = tn + wn * 64 + n * 16 + lr;
        float bc = b0[col];
#pragma unroll
        for (int jj = 0; jj < 4; ++jj)
          o[(size_t)(row0 + jj) * DM + col] = acc[m][n][jj] + bc;
      }
    }
  } else {
    const int sel = tn >> 10;                 // block-uniform (1024 % 256 == 0)
    const float* bias = sel == 0 ? b0 : sel == 1 ? b1 : b2;
    const float scl = sel == 0 ? qscale : 1.0f;
    unsigned short* dst = (unsigned short*)out + (size_t)sel * (8u << 20);
#pragma unroll
    for (int m = 0; m < 4; ++m) {
      int row0 = tm + wm * 64 + m * 16 + lg4 * 4;
#pragma unroll
      for (int n = 0; n < 4; ++n) {
        int col = tn + wn * 64 + n * 16 + lr;
        int c10 = col & 1023;
        int h = c10 >> 6, dd = c10 & 63;
        float bc = bias[c10];
#pragma unroll
        for (int jj = 0; jj < 4; ++jj) {
          float v = (acc[m][n][jj] + bc) * scl;
          int R = row0 + jj;
          int bb = R >> 11, ll = R & (L_SEQ - 1);
          if (sel < 2)
            dst[(((size_t)bb * NH + h) * L_SEQ + ll) * DK + dd] = f2bf(v);
          else
            dst[(((size_t)bb * NH + h) * DK + dd) * L_SEQ + ll] = f2bf(v);
        }
      }
    }
  }
}

// ---------------- flash attention: swapped 32x32, 32 q/wave ----------------
// Q,K: [B,H,L,DK] bf16 (Q pre-scaled by 0.125*log2e). VT: [B,H,DK,L] bf16.
// DIAGNOSTIC: dispatched in 2 q-halves (qoff) so gemm8 surfaces in top-5.
#define KVB 64
#define LDK 68                 // 34-dword rows -> <=2-way banks (free)
#define NTILE (L_SEQ / KVB)
#define CLIP2 144.269504f      // 100*log2(e)
#define THR2  11.5415f         // 8*log2(e)

__device__ __forceinline__ bf16x8 lds_frag(const unsigned short* p) {
  uint2 a = *(const uint2*)p;
  uint2 b = *(const uint2*)(p + 4);
  u32x4 t = {a.x, a.y, b.x, b.y};
  return __builtin_bit_cast(bf16x8, t);
}

__device__ __forceinline__ void lds_st16(unsigned short* p, uint4 v) {
  *(uint2*)p = make_uint2(v.x, v.y);
  *(uint2*)(p + 4) = make_uint2(v.z, v.w);
}

// D.lo16 = bf16(a), D.hi16 = bf16(b)
__device__ __forceinline__ unsigned cvtpk(float a, float b) {
  unsigned r;
  asm("v_cvt_pk_bf16_f32 %0, %1, %2" : "=v"(r) : "v"(a), "v"(b));
  return r;
}

// a' = {a.lo32lanes, b.lo32lanes}; b' = {a.hi32lanes, b.hi32lanes}
// Round-3-VERIFIED shfl implementation.
__device__ __forceinline__ void pl32swap(unsigned& a, unsigned& b) {
  unsigned sa = (unsigned)__shfl_xor((int)a, 32);
  unsigned sb = (unsigned)__shfl_xor((int)b, 32);
  int hi = (threadIdx.x & 63) >> 5;
  unsigned na = hi ? sb : a;
  unsigned nb = hi ? b : sa;
  a = na; b = nb;
}

// every lane gets (x[lane&31], x[(lane&31)+32])
__device__ __forceinline__ void xpair32(float x, float& lo, float& hi2) {
  unsigned a = __builtin_bit_cast(unsigned, x), b = a;
  pl32swap(a, b);
  lo = __builtin_bit_cast(float, a);
  hi2 = __builtin_bit_cast(float, b);
}

#define MFMA32(a, b, c) __builtin_amdgcn_mfma_f32_32x32x16_bf16(a, b, c, 0, 0, 0)

__global__ __launch_bounds__(256, 4) void flash_attn(
    const unsigned short* __restrict__ Qg,
    const unsigned short* __restrict__ Kg,
    const unsigned short* __restrict__ VTg,
    unsigned short* __restrict__ ctx, int qoff) {
  __shared__ unsigned short Ks[2][64 * LDK];
  __shared__ unsigned short Vs[2][64 * LDK];

  const int bh = blockIdx.x, b = bh >> 4, h = bh & 15;
  const int q0 = (blockIdx.y + qoff) * 128;
  const int tid = threadIdx.x;
  const int w = tid >> 6, lane = tid & 63;
  const int l31 = lane & 31, hi = lane >> 5;
  const size_t head = (size_t)bh * (L_SEQ * DK);

  const int srow = w * 16 + (lane >> 2);     // staging row (4 waves cover 64)
  const int scol = (lane & 3) * 16;

  // Q fragments (B-operand layout: col=lane&31, k=hi*8+j), 32 q rows/wave
  bf16x8 qf[4];
  {
    const unsigned short* qp = Qg + head + (size_t)(q0 + w * 32 + l31) * DK + hi * 8;
#pragma unroll
    for (int ks = 0; ks < 4; ++ks) qf[ks] = *(const bf16x8*)(qp + ks * 16);
  }

  f32x16 o[2];
  o[0] = (f32x16)0.0f; o[1] = (f32x16)0.0f;
  float mq = -1e30f, lq = 0.0f;

  { // prologue: stage tile 0 into buffer 0
    const unsigned short* kp = Kg + head + (size_t)srow * DK + scol;
    uint4 k0 = *(const uint4*)kp, k1 = *(const uint4*)(kp + 8);
    const unsigned short* vp = VTg + head + (size_t)srow * L_SEQ + scol;
    uint4 v0 = *(const uint4*)vp, v1 = *(const uint4*)(vp + 8);
    lds_st16(Ks[0] + srow * LDK + scol, k0);
    lds_st16(Ks[0] + srow * LDK + scol + 8, k1);
    lds_st16(Vs[0] + srow * LDK + scol, v0);
    lds_st16(Vs[0] + srow * LDK + scol + 8, v1);
  }
  __syncthreads();

  int cur = 0;
  for (int t = 0; t < NTILE; ++t) {
    uint4 kr0, kr1, vr0, vr1;
    const int kv0n = (t + 1) * KVB;
    // (a) issue next K loads early (HBM/L2 latency hides under QK+softmax)
    if (t + 1 < NTILE) {
      const unsigned short* kp = Kg + head + (size_t)(kv0n + srow) * DK + scol;
      kr0 = *(const uint4*)kp; kr1 = *(const uint4*)(kp + 8);
    }

    // (b) QK^T: S[kv][q], lane's q = l31
    f32x16 s0 = (f32x16)0.0f, s1 = (f32x16)0.0f;
#pragma unroll
    for (int ks = 0; ks < 4; ++ks) {
      bf16x8 k0 = lds_frag(Ks[cur] + l31 * LDK + ks * 16 + hi * 8);
      s0 = MFMA32(k0, qf[ks], s0);
      bf16x8 k1 = lds_frag(Ks[cur] + (32 + l31) * LDK + ks * 16 + hi * 8);
      s1 = MFMA32(k1, qf[ks], s1);
    }

    // (c) clip + tile max: med3 clamp, TREE reduce
    float tm[16];
#pragma unroll
    for (int r = 0; r < 16; ++r) {
      s0[r] = __builtin_amdgcn_fmed3f(s0[r], -CLIP2, CLIP2);
      s1[r] = __builtin_amdgcn_fmed3f(s1[r], -CLIP2, CLIP2);
      tm[r] = fmaxf(s0[r], s1[r]);
    }
#pragma unroll
    for (int st = 8; st >= 1; st >>= 1)
#pragma unroll
      for (int r = 0; r < st; ++r) tm[r] = fmaxf(tm[r], tm[r + st]);
    float tmax;
    {
      float a, c; xpair32(tm[0], a, c);
      tmax = fmaxf(a, c);
    }
    // defer-max (T13)
    if (!__all(tmax - mq <= THR2)) {
      float mn = fmaxf(mq, tmax);
      float corr = EXP2F(mq - mn);
      lq *= corr;
#pragma unroll
      for (int r = 0; r < 16; ++r) { o[0][r] *= corr; o[1][r] *= corr; }
      mq = mn;
    }
#pragma unroll
    for (int r = 0; r < 16; ++r) {
      s0[r] = EXP2F(s0[r] - mq);
      s1[r] = EXP2F(s1[r] - mq);
    }
    // ls TREE sum
    float l4[4];
#pragma unroll
    for (int r = 0; r < 4; ++r)
      l4[r] = ((s0[r] + s0[r + 4]) + (s0[r + 8] + s0[r + 12]))
            + ((s1[r] + s1[r + 4]) + (s1[r + 8] + s1[r + 12]));
    float ls = (l4[0] + l4[1]) + (l4[2] + l4[3]);
    {
      float a, c; xpair32(ls, a, c);
      lq += a + c;
    }

    // (d) pack P into PV B-frags: frag[ks] elem j <- P[kv=16ks+8hi+j][q]
    bf16x8 pa[4];
#pragma unroll
    for (int ks = 0; ks < 4; ++ks) {
      const int s8 = (ks & 1) * 8;
      const f32x16 sv = (ks < 2) ? s0 : s1;
      unsigned uA0 = cvtpk(sv[s8 + 0], sv[s8 + 1]);
      unsigned uA1 = cvtpk(sv[s8 + 2], sv[s8 + 3]);
      unsigned uB0 = cvtpk(sv[s8 + 4], sv[s8 + 5]);
      unsigned uB1 = cvtpk(sv[s8 + 6], sv[s8 + 7]);
      pl32swap(uA0, uB0);
      pl32swap(uA1, uB1);
      u32x4 tt = {uA0, uA1, uB0, uB1};
      pa[ks] = __builtin_bit_cast(bf16x8, tt);
    }

    // (e) issue next V loads (hides under PV MFMAs)
    if (t + 1 < NTILE) {
      const unsigned short* vp = VTg + head + (size_t)srow * L_SEQ + kv0n + scol;
      vr0 = *(const uint4*)vp; vr1 = *(const uint4*)(vp + 8);
    }

    // (f) PV: O^T[d][q] += VT[d][kv] * P^T[q][kv]
#pragma unroll
    for (int jb = 0; jb < 2; ++jb)
#pragma unroll
      for (int ks = 0; ks < 4; ++ks) {
        bf16x8 vf = lds_frag(Vs[cur] + (32 * jb + l31) * LDK + ks * 16 + hi * 8);
        o[jb] = MFMA32(vf, pa[ks], o[jb]);
      }

    // (g) write staged regs into the OTHER buffer; one barrier publishes it
    if (t + 1 < NTILE) {
      lds_st16(Ks[cur ^ 1] + srow * LDK + scol, kr0);
      lds_st16(Ks[cur ^ 1] + srow * LDK + scol + 8, kr1);
      lds_st16(Vs[cur ^ 1] + srow * LDK + scol, vr0);
      lds_st16(Vs[cur ^ 1] + srow * LDK + scol + 8, vr1);
    }
    __syncthreads();
    cur ^= 1;
  }

  // epilogue: normalize, write ctx[token, h*64+d]
  {
    float inv = 1.0f / lq;
    const int tok = q0 + w * 32 + l31;
    size_t base = ((size_t)b * L_SEQ + tok) * DM + h * DK;
#pragma unroll
    for (int jb = 0; jb < 2; ++jb)
#pragma unroll
      for (int c = 0; c < 4; ++c) {
        ushort4 pk;   // regs 4c..4c+3 -> d = 32jb + 8c + 4hi + 0..3
        pk.x = f2bf(o[jb][4 * c + 0] * inv);
        pk.y = f2bf(o[jb][4 * c + 1] * inv);
        pk.z = f2bf(o[jb][4 * c + 2] * inv);
        pk.w = f2bf(o[jb][4 * c + 3] * inv);
        *(ushort4*)&ctx[base + jb * 32 + c * 8 + hi * 4] = pk;
      }
  }
}

// ---------------- launch ----------------
extern "C" void kernel_launch(void* const* d_in, const int* in_sizes, int n_in,
                              void* d_out, int out_size, void* d_ws, size_t ws_size,
                              hipStream_t stream) {
  (void)in_sizes; (void)n_in; (void)out_size; (void)ws_size;
  const float* x  = (const float*)d_in[0];
  const float* Wq = (const float*)d_in[1];
  const float* bq = (const float*)d_in[2];
  const float* Wk = (const float*)d_in[3];
  const float* bk = (const float*)d_in[4];
  const float* Wv = (const float*)d_in[5];
  const float* bv = (const float*)d_in[6];
  const float* Wo = (const float*)d_in[7];
  const float* bo = (const float*)d_in[8];

  char* ws = (char*)d_ws;
  unsigned short* xb  = (unsigned short*)(ws);                    // 16 MB
  unsigned short* wqb = (unsigned short*)(ws + (16ull << 20));    // wq|wk|wv|wo contiguous
  unsigned short* wob = (unsigned short*)(ws + (22ull << 20));
  unsigned short* Qb  = (unsigned short*)(ws + (24ull << 20));    // Q|K|VT, 16MB apart
  unsigned short* Kb  = (unsigned short*)(ws + (40ull << 20));
  unsigned short* VTb = (unsigned short*)(ws + (56ull << 20));
  unsigned short* ctx = xb;

  cvt_f32_bf16<<<2048, 256, 0, stream>>>(x, xb, M_TOK * DM / 4);
  cvt_w4<<<4096, 256, 0, stream>>>(Wq, Wk, Wv, Wo, wqb);

  // Fused QKV projection (2-phase deep pipeline); Q scaled by 0.125*log2(e)
  gemm8<0><<<dim3(3 * DM / GBN, M_TOK / GBM), 512, 0, stream>>>(
      xb, wqb, bq, bk, bv, 0.1803368801f, Qb);

  // DIAGNOSTIC split: two q-halves so gemm8 dispatches surface in rocprof top-5
  dim3 ga(BATCH * NH, L_SEQ / 128 / 2);
  flash_attn<<<ga, 256, 0, stream>>>(Qb, Kb, VTb, ctx, 0);
  flash_attn<<<ga, 256, 0, stream>>>(Qb, Kb, VTb, ctx, 8);

  gemm8<1><<<dim3(DM / GBN, M_TOK / GBM), 512, 0, stream>>>(
      ctx, wob, bo, nullptr, nullptr, 1.0f, d_out);
}

// Round 11
// 210.479 us; speedup vs baseline: 1.1838x; 1.1838x over previous
//
#include <hip/hip_runtime.h>
#include <stdint.h>

#define L_SEQ   2048
#define DM      1024
#define NH      16
#define DK      64
#define BATCH   4
#define M_TOK   (BATCH * L_SEQ)   // 8192

typedef __attribute__((ext_vector_type(8))) short bf16x8;
typedef __attribute__((ext_vector_type(4))) float f32x4;
typedef __attribute__((ext_vector_type(16))) float f32x16;
typedef __attribute__((ext_vector_type(4))) unsigned int u32x4;

typedef __attribute__((address_space(1))) void void_g;
typedef __attribute__((address_space(3))) void void_l;

#define EXP2F(x) __builtin_amdgcn_exp2f(x)

__device__ __forceinline__ unsigned short f2bf(float f) {
  unsigned int u = __builtin_bit_cast(unsigned int, f);
  u += 0x7FFFu + ((u >> 16) & 1u);
  return (unsigned short)(u >> 16);
}

// ---------------- fp32 -> bf16 converts ----------------
__global__ void cvt_f32_bf16(const float* __restrict__ src,
                             unsigned short* __restrict__ dst, int n4) {
  int i = blockIdx.x * blockDim.x + threadIdx.x;
  int stride = gridDim.x * blockDim.x;
  for (; i < n4; i += stride) {
    float4 v = ((const float4*)src)[i];
    ushort4 o;
    o.x = f2bf(v.x); o.y = f2bf(v.y); o.z = f2bf(v.z); o.w = f2bf(v.w);
    ((ushort4*)dst)[i] = o;
  }
}

// 4 weight matrices (1024x1024 each) -> contiguous bf16 dst, one launch
__global__ void cvt_w4(const float* __restrict__ s0, const float* __restrict__ s1,
                       const float* __restrict__ s2, const float* __restrict__ s3,
                       unsigned short* __restrict__ dst) {
  int i = blockIdx.x * blockDim.x + threadIdx.x;      // 0 .. 4*262144-1
  int sel = i >> 18, j = i & 0x3FFFF;
  const float* s = sel == 0 ? s0 : sel == 1 ? s1 : sel == 2 ? s2 : s3;
  float4 v = ((const float4*)s)[j];
  ushort4 o;
  o.x = f2bf(v.x); o.y = f2bf(v.y); o.z = f2bf(v.z); o.w = f2bf(v.w);
  ((ushort4*)(dst + (size_t)sel * DM * DM))[j] = o;
}

// ---------------- deep-pipelined GEMM, 2-phase/K-tile (T2+T3+T4+T5) -------
// Main loop frozen from R9/R10. NEW: LDS-repack epilogues for EPI 0 so all
// global stores are 16B coalesced (old: 2B scalar stores, V at stride 4KB).
#define GBM 128
#define GBN 256
#define GBK 64
#define NKT (DM / GBK)            // 16 K-tiles
#define ATILE (GBM * GBK)         // 8192 elems
#define BTILE (GBN * GBK)         // 16384 elems
#define BUFE (ATILE + BTILE)      // 24576 elems per buffer

__device__ __forceinline__ void stage_A(
    const unsigned short* __restrict__ A, unsigned short* buf,
    int tm, int k0, int t) {
  const int l = t & 63, w = t >> 6;
  const int su = (l & 7) ^ (l >> 3);          // pre-swizzled source unit
  const int rw = w * 8 + (l >> 3);
  const unsigned short* asrc = A + (size_t)(tm + rw) * DM + k0 + su * 8;
#pragma unroll
  for (int r = 0; r < 2; ++r)                 // A: 128 rows = 2 rounds
    __builtin_amdgcn_global_load_lds(
        (const void_g*)(asrc + (size_t)r * 64 * DM),
        (void_l*)(buf + r * 4096 + w * 512), 16, 0, 0);
}

__device__ __forceinline__ void stage_B(
    const unsigned short* __restrict__ Bw, unsigned short* buf,
    int tn, int k0, int t) {
  const int l = t & 63, w = t >> 6;
  const int su = (l & 7) ^ (l >> 3);
  const int rw = w * 8 + (l >> 3);
  const unsigned short* bsrc = Bw + (size_t)(tn + rw) * DM + k0 + su * 8;
#pragma unroll
  for (int r = 0; r < 4; ++r)                 // B: 256 rows = 4 rounds
    __builtin_amdgcn_global_load_lds(
        (const void_g*)(bsrc + (size_t)r * 64 * DM),
        (void_l*)(buf + ATILE + r * 4096 + w * 512), 16, 0, 0);
}

__device__ __forceinline__ bf16x8 frag_ld(const unsigned short* base, int R, int u) {
  return *(const bf16x8*)(base + R * 64 + (u ^ (R & 7)) * 8);
}

// EPI 0: QKV-split epilogue (bf16, head layouts, LDS-repacked stores).
// EPI 1: fp32 out + bias (direct stores, 64B segments).
template <int EPI>
__global__ __launch_bounds__(512, 2) void gemm8(
    const unsigned short* __restrict__ A,
    const unsigned short* __restrict__ Bw,
    const float* __restrict__ b0, const float* __restrict__ b1,
    const float* __restrict__ b2, float qscale,
    void* __restrict__ out) {
  __shared__ unsigned short L[3 * BUFE];      // 147456 B

  const int tidx = threadIdx.x;
  const int wid = tidx >> 6, lane = tidx & 63;
  const int wm = wid >> 2, wn = wid & 3;      // 2M x 4N
  const int lr = lane & 15, lg4 = lane >> 4;

  // bijective XCD swizzle (nwg % 8 == 0 for both grids)
  int wg = blockIdx.y * gridDim.x + blockIdx.x;
  int nwg = gridDim.x * gridDim.y;
  int swz = (wg & 7) * (nwg >> 3) + (wg >> 3);
  const int tm = (swz / gridDim.x) * GBM, tn = (swz % gridDim.x) * GBN;

  f32x4 acc[4][4];
#pragma unroll
  for (int m = 0; m < 4; ++m)
#pragma unroll
    for (int n = 0; n < 4; ++n) acc[m][n] = (f32x4)0.0f;

  // prologue: 2 tiles in flight (6 loads/thread each)
  stage_A(A, L, tm, 0, tidx);
  stage_B(Bw, L, tn, 0, tidx);
  stage_A(A, L + BUFE, tm, GBK, tidx);
  stage_B(Bw, L + BUFE, tn, GBK, tidx);
  asm volatile("s_waitcnt vmcnt(6)" ::: "memory");   // tile0 landed
  __builtin_amdgcn_s_barrier();

  for (int i = 0; i < NKT; ++i) {
    unsigned short* cb = L + (i % 3) * BUFE;
    unsigned short* nb = L + ((i + 2) % 3) * BUFE;
    const bool pf = (i + 2 < NKT);
    const int kn = (i + 2) * GBK;

    // ---- phase A (kk=0): ds-load subtile || stage-A issue -> MFMA cluster
    bf16x8 a0[4], bv0[4];
#pragma unroll
    for (int m = 0; m < 4; ++m)
      a0[m] = frag_ld(cb, wm * 64 + m * 16 + lr, lg4);
#pragma unroll
    for (int n = 0; n < 4; ++n)
      bv0[n] = frag_ld(cb + ATILE, wn * 64 + n * 16 + lr, lg4);
    if (pf) stage_A(A, nb, tm, kn, tidx);
    __builtin_amdgcn_s_barrier();
    asm volatile("s_waitcnt lgkmcnt(0)" ::: "memory");
    __builtin_amdgcn_s_setprio(1);
#pragma unroll
    for (int m = 0; m < 4; ++m)
#pragma unroll
      for (int n = 0; n < 4; ++n)
        acc[m][n] = __builtin_amdgcn_mfma_f32_16x16x32_bf16(a0[m], bv0[n], acc[m][n], 0, 0, 0);
    __builtin_amdgcn_s_setprio(0);
    __builtin_amdgcn_s_barrier();

    // ---- phase B (kk=1): ds-load subtile || stage-B issue -> vmcnt -> MFMA
    bf16x8 a1[4], bv1[4];
#pragma unroll
    for (int m = 0; m < 4; ++m)
      a1[m] = frag_ld(cb, wm * 64 + m * 16 + lr, 4 + lg4);
#pragma unroll
    for (int n = 0; n < 4; ++n)
      bv1[n] = frag_ld(cb + ATILE, wn * 64 + n * 16 + lr, 4 + lg4);
    if (pf) {
      stage_B(Bw, nb, tn, kn, tidx);
      asm volatile("s_waitcnt vmcnt(6)" ::: "memory");   // tile i+1 landed
    } else {
      asm volatile("s_waitcnt vmcnt(0)" ::: "memory");   // drain tail
    }
    __builtin_amdgcn_s_barrier();
    asm volatile("s_waitcnt lgkmcnt(0)" ::: "memory");
    __builtin_amdgcn_s_setprio(1);
#pragma unroll
    for (int m = 0; m < 4; ++m)
#pragma unroll
      for (int n = 0; n < 4; ++n)
        acc[m][n] = __builtin_amdgcn_mfma_f32_16x16x32_bf16(a1[m], bv1[n], acc[m][n], 0, 0, 0);
    __builtin_amdgcn_s_setprio(0);
    __builtin_amdgcn_s_barrier();
  }

  // epilogue
  if (EPI == 1) {
    float* o = (float*)out;
#pragma unroll
    for (int m = 0; m < 4; ++m) {
      int row0 = tm + wm * 64 + m * 16 + lg4 * 4;
#pragma unroll
      for (int n = 0; n < 4; ++n) {
        int col = tn + wn * 64 + n * 16 + lr;
        float bc = b0[col];
#pragma unroll
        for (int jj = 0; jj < 4; ++jj)
          o[(size_t)(row0 + jj) * DM + col] = acc[m][n][jj] + bc;
      }
    }
  } else {
    const int sel = tn >> 10;                 // block-uniform (1024 % 256 == 0)
    const float* bias = sel == 0 ? b0 : sel == 1 ? b1 : b2;
    const float scl = sel == 0 ? qscale : 1.0f;
    unsigned short* dst = (unsigned short*)out + (size_t)sel * (8u << 20);
    unsigned short* C = L;                    // reuse staging LDS
    const int bb = tm >> 11, l0 = tm & 2047;
    const int tnl = tn & 1023;

    if (sel < 2) {
      // row-major repack, row stride 264 elems (528B, 16B-aligned)
#pragma unroll
      for (int m = 0; m < 4; ++m) {
        int row0 = wm * 64 + m * 16 + lg4 * 4;
#pragma unroll
        for (int n = 0; n < 4; ++n) {
          int col = wn * 64 + n * 16 + lr;
          float bc = bias[tnl + col];
#pragma unroll
          for (int jj = 0; jj < 4; ++jj)
            C[(row0 + jj) * 264 + col] = f2bf((acc[m][n][jj] + bc) * scl);
        }
      }
      __syncthreads();
#pragma unroll
      for (int j = 0; j < 8; ++j) {
        int c = j * 512 + tidx;               // 0..4095 chunks of 8
        int ll = c >> 5, colc = (c & 31) * 8;
        bf16x8 v = *(const bf16x8*)&C[ll * 264 + colc];
        int c10 = tnl + colc;
        int h = c10 >> 6, dd = c10 & 63;      // 8 elems stay inside one head
        *(bf16x8*)&dst[(((size_t)bb * NH + h) * L_SEQ + (l0 + ll)) * DK + dd] = v;
      }
    } else {
      // V: dd-major (pre-transposed) repack, row stride 136 elems (272B)
#pragma unroll
      for (int m = 0; m < 4; ++m) {
        int row0 = wm * 64 + m * 16 + lg4 * 4;
#pragma unroll
        for (int n = 0; n < 4; ++n) {
          int col = wn * 64 + n * 16 + lr;
          float bc = bias[tnl + col];
          ushort4 pk;
          pk.x = f2bf(acc[m][n][0] + bc);
          pk.y = f2bf(acc[m][n][1] + bc);
          pk.z = f2bf(acc[m][n][2] + bc);
          pk.w = f2bf(acc[m][n][3] + bc);
          *(ushort4*)&C[col * 136 + row0] = pk;   // 8B write, 2-way banks
        }
      }
      __syncthreads();
#pragma unroll
      for (int j = 0; j < 8; ++j) {
        int c = j * 512 + tidx;               // 0..4095 chunks of 8 tokens
        int ddl = c >> 4, tk = (c & 15) * 8;
        bf16x8 v = *(const bf16x8*)&C[ddl * 136 + tk];
        int c10 = tnl + ddl;
        int h = c10 >> 6, dd = c10 & 63;
        *(bf16x8*)&dst[(((size_t)bb * NH + h) * DK + dd) * L_SEQ + (l0 + tk)] = v;
      }
    }
  }
}

// ---------------- flash attention: swapped 32x32, 32 q/wave ----------------
// Q,K: [B,H,L,DK] bf16 (Q pre-scaled by 0.125*log2e). VT: [B,H,DK,L] bf16.
#define KVB 64
#define LDK 68                 // 34-dword rows -> <=2-way banks (free)
#define NTILE (L_SEQ / KVB)
#define CLIP2 144.269504f      // 100*log2(e)
#define THR2  11.5415f         // 8*log2(e)

__device__ __forceinline__ bf16x8 lds_frag(const unsigned short* p) {
  uint2 a = *(const uint2*)p;
  uint2 b = *(const uint2*)(p + 4);
  u32x4 t = {a.x, a.y, b.x, b.y};
  return __builtin_bit_cast(bf16x8, t);
}

__device__ __forceinline__ void lds_st16(unsigned short* p, uint4 v) {
  *(uint2*)p = make_uint2(v.x, v.y);
  *(uint2*)(p + 4) = make_uint2(v.z, v.w);
}

// D.lo16 = bf16(a), D.hi16 = bf16(b)
__device__ __forceinline__ unsigned cvtpk(float a, float b) {
  unsigned r;
  asm("v_cvt_pk_bf16_f32 %0, %1, %2" : "=v"(r) : "v"(a), "v"(b));
  return r;
}

// a' = {a.lo32lanes, b.lo32lanes}; b' = {a.hi32lanes, b.hi32lanes}
// Round-3-VERIFIED shfl implementation.
__device__ __forceinline__ void pl32swap(unsigned& a, unsigned& b) {
  unsigned sa = (unsigned)__shfl_xor((int)a, 32);
  unsigned sb = (unsigned)__shfl_xor((int)b, 32);
  int hi = (threadIdx.x & 63) >> 5;
  unsigned na = hi ? sb : a;
  unsigned nb = hi ? b : sa;
  a = na; b = nb;
}

// every lane gets (x[lane&31], x[(lane&31)+32])
__device__ __forceinline__ void xpair32(float x, float& lo, float& hi2) {
  unsigned a = __builtin_bit_cast(unsigned, x), b = a;
  pl32swap(a, b);
  lo = __builtin_bit_cast(float, a);
  hi2 = __builtin_bit_cast(float, b);
}

#define MFMA32(a, b, c) __builtin_amdgcn_mfma_f32_32x32x16_bf16(a, b, c, 0, 0, 0)

__global__ __launch_bounds__(256, 4) void flash_attn(
    const unsigned short* __restrict__ Qg,
    const unsigned short* __restrict__ Kg,
    const unsigned short* __restrict__ VTg,
    unsigned short* __restrict__ ctx) {
  __shared__ unsigned short Ks[2][64 * LDK];
  __shared__ unsigned short Vs[2][64 * LDK];

  const int bh = blockIdx.x, b = bh >> 4, h = bh & 15;
  const int q0 = blockIdx.y * 128;
  const int tid = threadIdx.x;
  const int w = tid >> 6, lane = tid & 63;
  const int l31 = lane & 31, hi = lane >> 5;
  const size_t head = (size_t)bh * (L_SEQ * DK);

  const int srow = w * 16 + (lane >> 2);     // staging row (4 waves cover 64)
  const int scol = (lane & 3) * 16;

  // Q fragments (B-operand layout: col=lane&31, k=hi*8+j), 32 q rows/wave
  bf16x8 qf[4];
  {
    const unsigned short* qp = Qg + head + (size_t)(q0 + w * 32 + l31) * DK + hi * 8;
#pragma unroll
    for (int ks = 0; ks < 4; ++ks) qf[ks] = *(const bf16x8*)(qp + ks * 16);
  }

  f32x16 o[2];
  o[0] = (f32x16)0.0f; o[1] = (f32x16)0.0f;
  float mq = -1e30f, lq = 0.0f;

  { // prologue: stage tile 0 into buffer 0
    const unsigned short* kp = Kg + head + (size_t)srow * DK + scol;
    uint4 k0 = *(const uint4*)kp, k1 = *(const uint4*)(kp + 8);
    const unsigned short* vp = VTg + head + (size_t)srow * L_SEQ + scol;
    uint4 v0 = *(const uint4*)vp, v1 = *(const uint4*)(vp + 8);
    lds_st16(Ks[0] + srow * LDK + scol, k0);
    lds_st16(Ks[0] + srow * LDK + scol + 8, k1);
    lds_st16(Vs[0] + srow * LDK + scol, v0);
    lds_st16(Vs[0] + srow * LDK + scol + 8, v1);
  }
  __syncthreads();

  int cur = 0;
  for (int t = 0; t < NTILE; ++t) {
    uint4 kr0, kr1, vr0, vr1;
    const int kv0n = (t + 1) * KVB;
    // (a) issue next K loads early (HBM/L2 latency hides under QK+softmax)
    if (t + 1 < NTILE) {
      const unsigned short* kp = Kg + head + (size_t)(kv0n + srow) * DK + scol;
      kr0 = *(const uint4*)kp; kr1 = *(const uint4*)(kp + 8);
    }

    // (b) QK^T: S[kv][q], lane's q = l31
    f32x16 s0 = (f32x16)0.0f, s1 = (f32x16)0.0f;
#pragma unroll
    for (int ks = 0; ks < 4; ++ks) {
      bf16x8 k0 = lds_frag(Ks[cur] + l31 * LDK + ks * 16 + hi * 8);
      s0 = MFMA32(k0, qf[ks], s0);
      bf16x8 k1 = lds_frag(Ks[cur] + (32 + l31) * LDK + ks * 16 + hi * 8);
      s1 = MFMA32(k1, qf[ks], s1);
    }

    // (c) clip + tile max: med3 clamp, TREE reduce
    float tm[16];
#pragma unroll
    for (int r = 0; r < 16; ++r) {
      s0[r] = __builtin_amdgcn_fmed3f(s0[r], -CLIP2, CLIP2);
      s1[r] = __builtin_amdgcn_fmed3f(s1[r], -CLIP2, CLIP2);
      tm[r] = fmaxf(s0[r], s1[r]);
    }
#pragma unroll
    for (int st = 8; st >= 1; st >>= 1)
#pragma unroll
      for (int r = 0; r < st; ++r) tm[r] = fmaxf(tm[r], tm[r + st]);
    float tmax;
    {
      float a, c; xpair32(tm[0], a, c);
      tmax = fmaxf(a, c);
    }
    // defer-max (T13)
    if (!__all(tmax - mq <= THR2)) {
      float mn = fmaxf(mq, tmax);
      float corr = EXP2F(mq - mn);
      lq *= corr;
#pragma unroll
      for (int r = 0; r < 16; ++r) { o[0][r] *= corr; o[1][r] *= corr; }
      mq = mn;
    }
#pragma unroll
    for (int r = 0; r < 16; ++r) {
      s0[r] = EXP2F(s0[r] - mq);
      s1[r] = EXP2F(s1[r] - mq);
    }
    // ls TREE sum
    float l4[4];
#pragma unroll
    for (int r = 0; r < 4; ++r)
      l4[r] = ((s0[r] + s0[r + 4]) + (s0[r + 8] + s0[r + 12]))
            + ((s1[r] + s1[r + 4]) + (s1[r + 8] + s1[r + 12]));
    float ls = (l4[0] + l4[1]) + (l4[2] + l4[3]);
    {
      float a, c; xpair32(ls, a, c);
      lq += a + c;
    }

    // (d) pack P into PV B-frags: frag[ks] elem j <- P[kv=16ks+8hi+j][q]
    bf16x8 pa[4];
#pragma unroll
    for (int ks = 0; ks < 4; ++ks) {
      const int s8 = (ks & 1) * 8;
      const f32x16 sv = (ks < 2) ? s0 : s1;
      unsigned uA0 = cvtpk(sv[s8 + 0], sv[s8 + 1]);
      unsigned uA1 = cvtpk(sv[s8 + 2], sv[s8 + 3]);
      unsigned uB0 = cvtpk(sv[s8 + 4], sv[s8 + 5]);
      unsigned uB1 = cvtpk(sv[s8 + 6], sv[s8 + 7]);
      pl32swap(uA0, uB0);
      pl32swap(uA1, uB1);
      u32x4 tt = {uA0, uA1, uB0, uB1};
      pa[ks] = __builtin_bit_cast(bf16x8, tt);
    }

    // (e) issue next V loads (hides under PV MFMAs)
    if (t + 1 < NTILE) {
      const unsigned short* vp = VTg + head + (size_t)srow * L_SEQ + kv0n + scol;
      vr0 = *(const uint4*)vp; vr1 = *(const uint4*)(vp + 8);
    }

    // (f) PV: O^T[d][q] += VT[d][kv] * P^T[q][kv]
#pragma unroll
    for (int jb = 0; jb < 2; ++jb)
#pragma unroll
      for (int ks = 0; ks < 4; ++ks) {
        bf16x8 vf = lds_frag(Vs[cur] + (32 * jb + l31) * LDK + ks * 16 + hi * 8);
        o[jb] = MFMA32(vf, pa[ks], o[jb]);
      }

    // (g) write staged regs into the OTHER buffer; one barrier publishes it
    if (t + 1 < NTILE) {
      lds_st16(Ks[cur ^ 1] + srow * LDK + scol, kr0);
      lds_st16(Ks[cur ^ 1] + srow * LDK + scol + 8, kr1);
      lds_st16(Vs[cur ^ 1] + srow * LDK + scol, vr0);
      lds_st16(Vs[cur ^ 1] + srow * LDK + scol + 8, vr1);
    }
    __syncthreads();
    cur ^= 1;
  }

  // epilogue: normalize, write ctx[token, h*64+d]
  {
    float inv = 1.0f / lq;
    const int tok = q0 + w * 32 + l31;
    size_t base = ((size_t)b * L_SEQ + tok) * DM + h * DK;
#pragma unroll
    for (int jb = 0; jb < 2; ++jb)
#pragma unroll
      for (int c = 0; c < 4; ++c) {
        ushort4 pk;   // regs 4c..4c+3 -> d = 32jb + 8c + 4hi + 0..3
        pk.x = f2bf(o[jb][4 * c + 0] * inv);
        pk.y = f2bf(o[jb][4 * c + 1] * inv);
        pk.z = f2bf(o[jb][4 * c + 2] * inv);
        pk.w = f2bf(o[jb][4 * c + 3] * inv);
        *(ushort4*)&ctx[base + jb * 32 + c * 8 + hi * 4] = pk;
      }
  }
}

// ---------------- launch ----------------
extern "C" void kernel_launch(void* const* d_in, const int* in_sizes, int n_in,
                              void* d_out, int out_size, void* d_ws, size_t ws_size,
                              hipStream_t stream) {
  (void)in_sizes; (void)n_in; (void)out_size; (void)ws_size;
  const float* x  = (const float*)d_in[0];
  const float* Wq = (const float*)d_in[1];
  const float* bq = (const float*)d_in[2];
  const float* Wk = (const float*)d_in[3];
  const float* bk = (const float*)d_in[4];
  const float* Wv = (const float*)d_in[5];
  const float* bv = (const float*)d_in[6];
  const float* Wo = (const float*)d_in[7];
  const float* bo = (const float*)d_in[8];

  char* ws = (char*)d_ws;
  unsigned short* xb  = (unsigned short*)(ws);                    // 16 MB
  unsigned short* wqb = (unsigned short*)(ws + (16ull << 20));    // wq|wk|wv|wo contiguous
  unsigned short* wob = (unsigned short*)(ws + (22ull << 20));
  unsigned short* Qb  = (unsigned short*)(ws + (24ull << 20));    // Q|K|VT, 16MB apart
  unsigned short* Kb  = (unsigned short*)(ws + (40ull << 20));
  unsigned short* VTb = (unsigned short*)(ws + (56ull << 20));
  unsigned short* ctx = xb;

  cvt_f32_bf16<<<2048, 256, 0, stream>>>(x, xb, M_TOK * DM / 4);
  cvt_w4<<<4096, 256, 0, stream>>>(Wq, Wk, Wv, Wo, wqb);

  // Fused QKV projection (2-phase deep pipeline); Q scaled by 0.125*log2(e)
  gemm8<0><<<dim3(3 * DM / GBN, M_TOK / GBM), 512, 0, stream>>>(
      xb, wqb, bq, bk, bv, 0.1803368801f, Qb);

  dim3 ga(BATCH * NH, L_SEQ / 128);
  flash_attn<<<ga, 256, 0, stream>>>(Qb, Kb, VTb, ctx);

  gemm8<1><<<dim3(DM / GBN, M_TOK / GBM), 512, 0, stream>>>(
      ctx, wob, bo, nullptr, nullptr, 1.0f, d_out);
}

// Round 12
// 200.527 us; speedup vs baseline: 1.2425x; 1.0496x over previous
//
#include <hip/hip_runtime.h>
#include <stdint.h>

#define L_SEQ   2048
#define DM      1024
#define NH      16
#define DK      64
#define BATCH   4
#define M_TOK   (BATCH * L_SEQ)   // 8192

typedef __attribute__((ext_vector_type(8))) short bf16x8;
typedef __attribute__((ext_vector_type(4))) float f32x4;
typedef __attribute__((ext_vector_type(16))) float f32x16;
typedef __attribute__((ext_vector_type(4))) unsigned int u32x4;

typedef __attribute__((address_space(1))) void void_g;
typedef __attribute__((address_space(3))) void void_l;

#define EXP2F(x) __builtin_amdgcn_exp2f(x)

__device__ __forceinline__ unsigned short f2bf(float f) {
  unsigned int u = __builtin_bit_cast(unsigned int, f);
  u += 0x7FFFu + ((u >> 16) & 1u);
  return (unsigned short)(u >> 16);
}

// ---------------- fp32 -> bf16 converts ----------------
__global__ void cvt_f32_bf16(const float* __restrict__ src,
                             unsigned short* __restrict__ dst, int n4) {
  int i = blockIdx.x * blockDim.x + threadIdx.x;
  int stride = gridDim.x * blockDim.x;
  for (; i < n4; i += stride) {
    float4 v = ((const float4*)src)[i];
    ushort4 o;
    o.x = f2bf(v.x); o.y = f2bf(v.y); o.z = f2bf(v.z); o.w = f2bf(v.w);
    ((ushort4*)dst)[i] = o;
  }
}

// 4 weight matrices (1024x1024 each) -> contiguous bf16 dst, one launch
__global__ void cvt_w4(const float* __restrict__ s0, const float* __restrict__ s1,
                       const float* __restrict__ s2, const float* __restrict__ s3,
                       unsigned short* __restrict__ dst) {
  int i = blockIdx.x * blockDim.x + threadIdx.x;      // 0 .. 4*262144-1
  int sel = i >> 18, j = i & 0x3FFFF;
  const float* s = sel == 0 ? s0 : sel == 1 ? s1 : sel == 2 ? s2 : s3;
  float4 v = ((const float4*)s)[j];
  ushort4 o;
  o.x = f2bf(v.x); o.y = f2bf(v.y); o.z = f2bf(v.z); o.w = f2bf(v.w);
  ((ushort4*)(dst + (size_t)sel * DM * DM))[j] = o;
}

// ---------------- deep-pipelined GEMM, 2-phase/K-tile (T2+T3+T4+T5) -------
// (frozen from R11)
#define GBM 128
#define GBN 256
#define GBK 64
#define NKT (DM / GBK)            // 16 K-tiles
#define ATILE (GBM * GBK)         // 8192 elems
#define BTILE (GBN * GBK)         // 16384 elems
#define BUFE (ATILE + BTILE)      // 24576 elems per buffer

__device__ __forceinline__ void stage_A(
    const unsigned short* __restrict__ A, unsigned short* buf,
    int tm, int k0, int t) {
  const int l = t & 63, w = t >> 6;
  const int su = (l & 7) ^ (l >> 3);          // pre-swizzled source unit
  const int rw = w * 8 + (l >> 3);
  const unsigned short* asrc = A + (size_t)(tm + rw) * DM + k0 + su * 8;
#pragma unroll
  for (int r = 0; r < 2; ++r)                 // A: 128 rows = 2 rounds
    __builtin_amdgcn_global_load_lds(
        (const void_g*)(asrc + (size_t)r * 64 * DM),
        (void_l*)(buf + r * 4096 + w * 512), 16, 0, 0);
}

__device__ __forceinline__ void stage_B(
    const unsigned short* __restrict__ Bw, unsigned short* buf,
    int tn, int k0, int t) {
  const int l = t & 63, w = t >> 6;
  const int su = (l & 7) ^ (l >> 3);
  const int rw = w * 8 + (l >> 3);
  const unsigned short* bsrc = Bw + (size_t)(tn + rw) * DM + k0 + su * 8;
#pragma unroll
  for (int r = 0; r < 4; ++r)                 // B: 256 rows = 4 rounds
    __builtin_amdgcn_global_load_lds(
        (const void_g*)(bsrc + (size_t)r * 64 * DM),
        (void_l*)(buf + ATILE + r * 4096 + w * 512), 16, 0, 0);
}

__device__ __forceinline__ bf16x8 frag_ld(const unsigned short* base, int R, int u) {
  return *(const bf16x8*)(base + R * 64 + (u ^ (R & 7)) * 8);
}

// EPI 0: QKV-split epilogue (bf16, head layouts, LDS-repacked stores).
// EPI 1: fp32 out + bias (direct stores, 64B segments).
template <int EPI>
__global__ __launch_bounds__(512, 2) void gemm8(
    const unsigned short* __restrict__ A,
    const unsigned short* __restrict__ Bw,
    const float* __restrict__ b0, const float* __restrict__ b1,
    const float* __restrict__ b2, float qscale,
    void* __restrict__ out) {
  __shared__ unsigned short L[3 * BUFE];      // 147456 B

  const int tidx = threadIdx.x;
  const int wid = tidx >> 6, lane = tidx & 63;
  const int wm = wid >> 2, wn = wid & 3;      // 2M x 4N
  const int lr = lane & 15, lg4 = lane >> 4;

  // bijective XCD swizzle (nwg % 8 == 0 for both grids)
  int wg = blockIdx.y * gridDim.x + blockIdx.x;
  int nwg = gridDim.x * gridDim.y;
  int swz = (wg & 7) * (nwg >> 3) + (wg >> 3);
  const int tm = (swz / gridDim.x) * GBM, tn = (swz % gridDim.x) * GBN;

  f32x4 acc[4][4];
#pragma unroll
  for (int m = 0; m < 4; ++m)
#pragma unroll
    for (int n = 0; n < 4; ++n) acc[m][n] = (f32x4)0.0f;

  // prologue: 2 tiles in flight (6 loads/thread each)
  stage_A(A, L, tm, 0, tidx);
  stage_B(Bw, L, tn, 0, tidx);
  stage_A(A, L + BUFE, tm, GBK, tidx);
  stage_B(Bw, L + BUFE, tn, GBK, tidx);
  asm volatile("s_waitcnt vmcnt(6)" ::: "memory");   // tile0 landed
  __builtin_amdgcn_s_barrier();

  for (int i = 0; i < NKT; ++i) {
    unsigned short* cb = L + (i % 3) * BUFE;
    unsigned short* nb = L + ((i + 2) % 3) * BUFE;
    const bool pf = (i + 2 < NKT);
    const int kn = (i + 2) * GBK;

    // ---- phase A (kk=0): ds-load subtile || stage-A issue -> MFMA cluster
    bf16x8 a0[4], bv0[4];
#pragma unroll
    for (int m = 0; m < 4; ++m)
      a0[m] = frag_ld(cb, wm * 64 + m * 16 + lr, lg4);
#pragma unroll
    for (int n = 0; n < 4; ++n)
      bv0[n] = frag_ld(cb + ATILE, wn * 64 + n * 16 + lr, lg4);
    if (pf) stage_A(A, nb, tm, kn, tidx);
    __builtin_amdgcn_s_barrier();
    asm volatile("s_waitcnt lgkmcnt(0)" ::: "memory");
    __builtin_amdgcn_s_setprio(1);
#pragma unroll
    for (int m = 0; m < 4; ++m)
#pragma unroll
      for (int n = 0; n < 4; ++n)
        acc[m][n] = __builtin_amdgcn_mfma_f32_16x16x32_bf16(a0[m], bv0[n], acc[m][n], 0, 0, 0);
    __builtin_amdgcn_s_setprio(0);
    __builtin_amdgcn_s_barrier();

    // ---- phase B (kk=1): ds-load subtile || stage-B issue -> vmcnt -> MFMA
    bf16x8 a1[4], bv1[4];
#pragma unroll
    for (int m = 0; m < 4; ++m)
      a1[m] = frag_ld(cb, wm * 64 + m * 16 + lr, 4 + lg4);
#pragma unroll
    for (int n = 0; n < 4; ++n)
      bv1[n] = frag_ld(cb + ATILE, wn * 64 + n * 16 + lr, 4 + lg4);
    if (pf) {
      stage_B(Bw, nb, tn, kn, tidx);
      asm volatile("s_waitcnt vmcnt(6)" ::: "memory");   // tile i+1 landed
    } else {
      asm volatile("s_waitcnt vmcnt(0)" ::: "memory");   // drain tail
    }
    __builtin_amdgcn_s_barrier();
    asm volatile("s_waitcnt lgkmcnt(0)" ::: "memory");
    __builtin_amdgcn_s_setprio(1);
#pragma unroll
    for (int m = 0; m < 4; ++m)
#pragma unroll
      for (int n = 0; n < 4; ++n)
        acc[m][n] = __builtin_amdgcn_mfma_f32_16x16x32_bf16(a1[m], bv1[n], acc[m][n], 0, 0, 0);
    __builtin_amdgcn_s_setprio(0);
    __builtin_amdgcn_s_barrier();
  }

  // epilogue
  if (EPI == 1) {
    float* o = (float*)out;
#pragma unroll
    for (int m = 0; m < 4; ++m) {
      int row0 = tm + wm * 64 + m * 16 + lg4 * 4;
#pragma unroll
      for (int n = 0; n < 4; ++n) {
        int col = tn + wn * 64 + n * 16 + lr;
        float bc = b0[col];
#pragma unroll
        for (int jj = 0; jj < 4; ++jj)
          o[(size_t)(row0 + jj) * DM + col] = acc[m][n][jj] + bc;
      }
    }
  } else {
    const int sel = tn >> 10;                 // block-uniform (1024 % 256 == 0)
    const float* bias = sel == 0 ? b0 : sel == 1 ? b1 : b2;
    const float scl = sel == 0 ? qscale : 1.0f;
    unsigned short* dst = (unsigned short*)out + (size_t)sel * (8u << 20);
    unsigned short* C = L;                    // reuse staging LDS
    const int bb = tm >> 11, l0 = tm & 2047;
    const int tnl = tn & 1023;

    if (sel < 2) {
      // row-major repack, row stride 264 elems (528B, 16B-aligned)
#pragma unroll
      for (int m = 0; m < 4; ++m) {
        int row0 = wm * 64 + m * 16 + lg4 * 4;
#pragma unroll
        for (int n = 0; n < 4; ++n) {
          int col = wn * 64 + n * 16 + lr;
          float bc = bias[tnl + col];
#pragma unroll
          for (int jj = 0; jj < 4; ++jj)
            C[(row0 + jj) * 264 + col] = f2bf((acc[m][n][jj] + bc) * scl);
        }
      }
      __syncthreads();
#pragma unroll
      for (int j = 0; j < 8; ++j) {
        int c = j * 512 + tidx;               // 0..4095 chunks of 8
        int ll = c >> 5, colc = (c & 31) * 8;
        bf16x8 v = *(const bf16x8*)&C[ll * 264 + colc];
        int c10 = tnl + colc;
        int h = c10 >> 6, dd = c10 & 63;      // 8 elems stay inside one head
        *(bf16x8*)&dst[(((size_t)bb * NH + h) * L_SEQ + (l0 + ll)) * DK + dd] = v;
      }
    } else {
      // V: dd-major (pre-transposed) repack, row stride 136 elems (272B)
#pragma unroll
      for (int m = 0; m < 4; ++m) {
        int row0 = wm * 64 + m * 16 + lg4 * 4;
#pragma unroll
        for (int n = 0; n < 4; ++n) {
          int col = wn * 64 + n * 16 + lr;
          float bc = bias[tnl + col];
          ushort4 pk;
          pk.x = f2bf(acc[m][n][0] + bc);
          pk.y = f2bf(acc[m][n][1] + bc);
          pk.z = f2bf(acc[m][n][2] + bc);
          pk.w = f2bf(acc[m][n][3] + bc);
          *(ushort4*)&C[col * 136 + row0] = pk;   // 8B write, 2-way banks
        }
      }
      __syncthreads();
#pragma unroll
      for (int j = 0; j < 8; ++j) {
        int c = j * 512 + tidx;               // 0..4095 chunks of 8 tokens
        int ddl = c >> 4, tk = (c & 15) * 8;
        bf16x8 v = *(const bf16x8*)&C[ddl * 136 + tk];
        int c10 = tnl + ddl;
        int h = c10 >> 6, dd = c10 & 63;
        *(bf16x8*)&dst[(((size_t)bb * NH + h) * DK + dd) * L_SEQ + (l0 + tk)] = v;
      }
    }
  }
}

// ---------------- flash attention: swapped 32x32, FIXED-MAX softmax -------
// Q,K: [B,H,L,DK] bf16 (Q pre-scaled by 0.125*log2e). VT: [B,H,DK,L] bf16.
// Scores clipped to +-144.27 (log2 domain) => exp2(s - 32) can never
// overflow fp32 (row sum <= 2048*2^112.3 = 2^123.3); softmax scale cancels.
// -M is folded into the MFMA C-init; clip bounds shift accordingly.
#define KVB 64
#define LDK 68                 // 34-dword rows -> <=2-way banks (free)
#define NTILE (L_SEQ / KVB)
#define FIXM  32.0f
#define CLO  (-144.269504f - FIXM)   // clip lo, shifted
#define CHI  (144.269504f - FIXM)    // clip hi, shifted

__device__ __forceinline__ bf16x8 lds_frag(const unsigned short* p) {
  uint2 a = *(const uint2*)p;
  uint2 b = *(const uint2*)(p + 4);
  u32x4 t = {a.x, a.y, b.x, b.y};
  return __builtin_bit_cast(bf16x8, t);
}

__device__ __forceinline__ void lds_st16(unsigned short* p, uint4 v) {
  *(uint2*)p = make_uint2(v.x, v.y);
  *(uint2*)(p + 4) = make_uint2(v.z, v.w);
}

// D.lo16 = bf16(a), D.hi16 = bf16(b)
__device__ __forceinline__ unsigned cvtpk(float a, float b) {
  unsigned r;
  asm("v_cvt_pk_bf16_f32 %0, %1, %2" : "=v"(r) : "v"(a), "v"(b));
  return r;
}

// a' = {a.lo32lanes, b.lo32lanes}; b' = {a.hi32lanes, b.hi32lanes}
// Round-3-VERIFIED shfl implementation.
__device__ __forceinline__ void pl32swap(unsigned& a, unsigned& b) {
  unsigned sa = (unsigned)__shfl_xor((int)a, 32);
  unsigned sb = (unsigned)__shfl_xor((int)b, 32);
  int hi = (threadIdx.x & 63) >> 5;
  unsigned na = hi ? sb : a;
  unsigned nb = hi ? b : sa;
  a = na; b = nb;
}

// every lane gets (x[lane&31], x[(lane&31)+32])
__device__ __forceinline__ void xpair32(float x, float& lo, float& hi2) {
  unsigned a = __builtin_bit_cast(unsigned, x), b = a;
  pl32swap(a, b);
  lo = __builtin_bit_cast(float, a);
  hi2 = __builtin_bit_cast(float, b);
}

#define MFMA32(a, b, c) __builtin_amdgcn_mfma_f32_32x32x16_bf16(a, b, c, 0, 0, 0)

__global__ __launch_bounds__(256, 4) void flash_attn(
    const unsigned short* __restrict__ Qg,
    const unsigned short* __restrict__ Kg,
    const unsigned short* __restrict__ VTg,
    unsigned short* __restrict__ ctx) {
  __shared__ unsigned short Ks[2][64 * LDK];
  __shared__ unsigned short Vs[2][64 * LDK];

  const int bh = blockIdx.x, b = bh >> 4, h = bh & 15;
  const int q0 = blockIdx.y * 128;
  const int tid = threadIdx.x;
  const int w = tid >> 6, lane = tid & 63;
  const int l31 = lane & 31, hi = lane >> 5;
  const size_t head = (size_t)bh * (L_SEQ * DK);

  const int srow = w * 16 + (lane >> 2);     // staging row (4 waves cover 64)
  const int scol = (lane & 3) * 16;

  // Q fragments (B-operand layout: col=lane&31, k=hi*8+j), 32 q rows/wave
  bf16x8 qf[4];
  {
    const unsigned short* qp = Qg + head + (size_t)(q0 + w * 32 + l31) * DK + hi * 8;
#pragma unroll
    for (int ks = 0; ks < 4; ++ks) qf[ks] = *(const bf16x8*)(qp + ks * 16);
  }

  f32x16 o[2];
  o[0] = (f32x16)0.0f; o[1] = (f32x16)0.0f;
  float lq = 0.0f;

  { // prologue: stage tile 0 into buffer 0
    const unsigned short* kp = Kg + head + (size_t)srow * DK + scol;
    uint4 k0 = *(const uint4*)kp, k1 = *(const uint4*)(kp + 8);
    const unsigned short* vp = VTg + head + (size_t)srow * L_SEQ + scol;
    uint4 v0 = *(const uint4*)vp, v1 = *(const uint4*)(vp + 8);
    lds_st16(Ks[0] + srow * LDK + scol, k0);
    lds_st16(Ks[0] + srow * LDK + scol + 8, k1);
    lds_st16(Vs[0] + srow * LDK + scol, v0);
    lds_st16(Vs[0] + srow * LDK + scol + 8, v1);
  }
  __syncthreads();

  int cur = 0;
  for (int t = 0; t < NTILE; ++t) {
    uint4 kr0, kr1, vr0, vr1;
    const int kv0n = (t + 1) * KVB;
    // (a) issue next K loads early (HBM/L2 latency hides under QK+softmax)
    if (t + 1 < NTILE) {
      const unsigned short* kp = Kg + head + (size_t)(kv0n + srow) * DK + scol;
      kr0 = *(const uint4*)kp; kr1 = *(const uint4*)(kp + 8);
    }

    // (b) QK^T: S[kv][q] - FIXM (C-init), lane's q = l31
    f32x16 s0 = (f32x16)(-FIXM), s1 = (f32x16)(-FIXM);
#pragma unroll
    for (int ks = 0; ks < 4; ++ks) {
      bf16x8 k0 = lds_frag(Ks[cur] + l31 * LDK + ks * 16 + hi * 8);
      s0 = MFMA32(k0, qf[ks], s0);
      bf16x8 k1 = lds_frag(Ks[cur] + (32 + l31) * LDK + ks * 16 + hi * 8);
      s1 = MFMA32(k1, qf[ks], s1);
    }

    // (c) clip (shifted bounds) + exp2 directly; no max tracking needed
    float ls = 0.0f;
#pragma unroll
    for (int r = 0; r < 16; ++r) {
      s0[r] = EXP2F(__builtin_amdgcn_fmed3f(s0[r], CLO, CHI));
      s1[r] = EXP2F(__builtin_amdgcn_fmed3f(s1[r], CLO, CHI));
    }
    // ls TREE sum
    {
      float l4[4];
#pragma unroll
      for (int r = 0; r < 4; ++r)
        l4[r] = ((s0[r] + s0[r + 4]) + (s0[r + 8] + s0[r + 12]))
              + ((s1[r] + s1[r + 4]) + (s1[r + 8] + s1[r + 12]));
      ls = (l4[0] + l4[1]) + (l4[2] + l4[3]);
      float a, c; xpair32(ls, a, c);
      lq += a + c;
    }

    // (d) pack P into PV B-frags: frag[ks] elem j <- P[kv=16ks+8hi+j][q]
    bf16x8 pa[4];
#pragma unroll
    for (int ks = 0; ks < 4; ++ks) {
      const int s8 = (ks & 1) * 8;
      const f32x16 sv = (ks < 2) ? s0 : s1;
      unsigned uA0 = cvtpk(sv[s8 + 0], sv[s8 + 1]);
      unsigned uA1 = cvtpk(sv[s8 + 2], sv[s8 + 3]);
      unsigned uB0 = cvtpk(sv[s8 + 4], sv[s8 + 5]);
      unsigned uB1 = cvtpk(sv[s8 + 6], sv[s8 + 7]);
      pl32swap(uA0, uB0);
      pl32swap(uA1, uB1);
      u32x4 tt = {uA0, uA1, uB0, uB1};
      pa[ks] = __builtin_bit_cast(bf16x8, tt);
    }

    // (e) issue next V loads (hides under PV MFMAs)
    if (t + 1 < NTILE) {
      const unsigned short* vp = VTg + head + (size_t)srow * L_SEQ + kv0n + scol;
      vr0 = *(const uint4*)vp; vr1 = *(const uint4*)(vp + 8);
    }

    // (f) PV: O^T[d][q] += VT[d][kv] * P^T[q][kv]
#pragma unroll
    for (int jb = 0; jb < 2; ++jb)
#pragma unroll
      for (int ks = 0; ks < 4; ++ks) {
        bf16x8 vf = lds_frag(Vs[cur] + (32 * jb + l31) * LDK + ks * 16 + hi * 8);
        o[jb] = MFMA32(vf, pa[ks], o[jb]);
      }

    // (g) write staged regs into the OTHER buffer; one barrier publishes it
    if (t + 1 < NTILE) {
      lds_st16(Ks[cur ^ 1] + srow * LDK + scol, kr0);
      lds_st16(Ks[cur ^ 1] + srow * LDK + scol + 8, kr1);
      lds_st16(Vs[cur ^ 1] + srow * LDK + scol, vr0);
      lds_st16(Vs[cur ^ 1] + srow * LDK + scol + 8, vr1);
    }
    __syncthreads();
    cur ^= 1;
  }

  // epilogue: normalize, write ctx[token, h*64+d]
  {
    float inv = 1.0f / lq;
    const int tok = q0 + w * 32 + l31;
    size_t base = ((size_t)b * L_SEQ + tok) * DM + h * DK;
#pragma unroll
    for (int jb = 0; jb < 2; ++jb)
#pragma unroll
      for (int c = 0; c < 4; ++c) {
        ushort4 pk;   // regs 4c..4c+3 -> d = 32jb + 8c + 4hi + 0..3
        pk.x = f2bf(o[jb][4 * c + 0] * inv);
        pk.y = f2bf(o[jb][4 * c + 1] * inv);
        pk.z = f2bf(o[jb][4 * c + 2] * inv);
        pk.w = f2bf(o[jb][4 * c + 3] * inv);
        *(ushort4*)&ctx[base + jb * 32 + c * 8 + hi * 4] = pk;
      }
  }
}

// ---------------- launch ----------------
extern "C" void kernel_launch(void* const* d_in, const int* in_sizes, int n_in,
                              void* d_out, int out_size, void* d_ws, size_t ws_size,
                              hipStream_t stream) {
  (void)in_sizes; (void)n_in; (void)out_size; (void)ws_size;
  const float* x  = (const float*)d_in[0];
  const float* Wq = (const float*)d_in[1];
  const float* bq = (const float*)d_in[2];
  const float* Wk = (const float*)d_in[3];
  const float* bk = (const float*)d_in[4];
  const float* Wv = (const float*)d_in[5];
  const float* bv = (const float*)d_in[6];
  const float* Wo = (const float*)d_in[7];
  const float* bo = (const float*)d_in[8];

  char* ws = (char*)d_ws;
  unsigned short* xb  = (unsigned short*)(ws);                    // 16 MB
  unsigned short* wqb = (unsigned short*)(ws + (16ull << 20));    // wq|wk|wv|wo contiguous
  unsigned short* wob = (unsigned short*)(ws + (22ull << 20));
  unsigned short* Qb  = (unsigned short*)(ws + (24ull << 20));    // Q|K|VT, 16MB apart
  unsigned short* Kb  = (unsigned short*)(ws + (40ull << 20));
  unsigned short* VTb = (unsigned short*)(ws + (56ull << 20));
  unsigned short* ctx = xb;

  cvt_f32_bf16<<<2048, 256, 0, stream>>>(x, xb, M_TOK * DM / 4);
  cvt_w4<<<4096, 256, 0, stream>>>(Wq, Wk, Wv, Wo, wqb);

  // Fused QKV projection (2-phase deep pipeline); Q scaled by 0.125*log2(e)
  gemm8<0><<<dim3(3 * DM / GBN, M_TOK / GBM), 512, 0, stream>>>(
      xb, wqb, bq, bk, bv, 0.1803368801f, Qb);

  dim3 ga(BATCH * NH, L_SEQ / 128);
  flash_attn<<<ga, 256, 0, stream>>>(Qb, Kb, VTb, ctx);

  gemm8<1><<<dim3(DM / GBN, M_TOK / GBM), 512, 0, stream>>>(
      ctx, wob, bo, nullptr, nullptr, 1.0f, d_out);
}

// Round 13
// 192.049 us; speedup vs baseline: 1.2974x; 1.0441x over previous
//
#include <hip/hip_runtime.h>
#include <stdint.h>

#define L_SEQ   2048
#define DM      1024
#define NH      16
#define DK      64
#define BATCH   4
#define M_TOK   (BATCH * L_SEQ)   // 8192

typedef __attribute__((ext_vector_type(8))) short bf16x8;
typedef __attribute__((ext_vector_type(4))) float f32x4;
typedef __attribute__((ext_vector_type(16))) float f32x16;
typedef __attribute__((ext_vector_type(4))) unsigned int u32x4;

typedef __attribute__((address_space(1))) void void_g;
typedef __attribute__((address_space(3))) void void_l;

#define EXP2F(x) __builtin_amdgcn_exp2f(x)

__device__ __forceinline__ unsigned short f2bf(float f) {
  unsigned int u = __builtin_bit_cast(unsigned int, f);
  u += 0x7FFFu + ((u >> 16) & 1u);
  return (unsigned short)(u >> 16);
}

// ---------------- fp32 -> bf16 converts ----------------
__global__ void cvt_f32_bf16(const float* __restrict__ src,
                             unsigned short* __restrict__ dst, int n4) {
  int i = blockIdx.x * blockDim.x + threadIdx.x;
  int stride = gridDim.x * blockDim.x;
  for (; i < n4; i += stride) {
    float4 v = ((const float4*)src)[i];
    ushort4 o;
    o.x = f2bf(v.x); o.y = f2bf(v.y); o.z = f2bf(v.z); o.w = f2bf(v.w);
    ((ushort4*)dst)[i] = o;
  }
}

// 4 weight matrices (1024x1024 each) -> contiguous bf16 dst, one launch
__global__ void cvt_w4(const float* __restrict__ s0, const float* __restrict__ s1,
                       const float* __restrict__ s2, const float* __restrict__ s3,
                       unsigned short* __restrict__ dst) {
  int i = blockIdx.x * blockDim.x + threadIdx.x;      // 0 .. 4*262144-1
  int sel = i >> 18, j = i & 0x3FFFF;
  const float* s = sel == 0 ? s0 : sel == 1 ? s1 : sel == 2 ? s2 : s3;
  float4 v = ((const float4*)s)[j];
  ushort4 o;
  o.x = f2bf(v.x); o.y = f2bf(v.y); o.z = f2bf(v.z); o.w = f2bf(v.w);
  ((ushort4*)(dst + (size_t)sel * DM * DM))[j] = o;
}

// ---------------- deep-pipelined GEMM, BK=32, 2 blocks/CU -----------------
// C = A[8192,1024] @ Bw[N,1024]^T. BM=128, BK=32 (64B rows, 4 x 16B units),
// 3 LDS buffers (EPI0: 72KB -> 2 blocks/CU; EPI1: 48KB), depth-2 prefetch,
// counted vmcnt, 1 barrier/K-tile. Swizzle: unit' = unit ^ ((row>>1)&3)
// (2 lanes/slot per quarter-wave = conflict-free); global_load_lds dest is
// linear, source pre-swizzled: su = (l&3)^((l>>3)&3), wave-independent.
#define GBK 32
#define NKT (DM / GBK)            // 32 K-tiles
#define AT32 (128 * GBK)          // 4096 elems per A tile

// Stage a tile of NCH*16 rows x 32 cols; NCH 1KB wave-chunks, NW waves.
template <int NW, int NCH>
__device__ __forceinline__ void stage32(
    const unsigned short* __restrict__ S, unsigned short* buf,
    int row0, int k0, int t) {
  const int l = t & 63, w = t >> 6;
  const int su = (l & 3) ^ ((l >> 3) & 3);
  const int rl = l >> 2;
#pragma unroll
  for (int r = 0; r < NCH / NW; ++r) {
    const int c = r * NW + w;
    __builtin_amdgcn_global_load_lds(
        (const void_g*)(S + (size_t)(row0 + c * 16 + rl) * DM + k0 + su * 8),
        (void_l*)(buf + c * 512), 16, 0, 0);
  }
}

__device__ __forceinline__ bf16x8 frag_ld32(const unsigned short* base, int R, int u) {
  return *(const bf16x8*)(base + R * 32 + ((u ^ ((R >> 1) & 3)) * 8));
}

// EPI 0: BN=256, 8 waves (2Mx4N), QKV-split epilogue via LDS repack.
// EPI 1: BN=128, 4 waves (2Mx2N), fp32 out + bias direct.
template <int EPI, int BN_, int NW>
__global__ __launch_bounds__(NW * 64, EPI == 0 ? 4 : 3) void gemm8(
    const unsigned short* __restrict__ A,
    const unsigned short* __restrict__ Bw,
    const float* __restrict__ b0, const float* __restrict__ b1,
    const float* __restrict__ b2, float qscale,
    void* __restrict__ out) {
  constexpr int BUFE = (128 + BN_) * GBK;
  constexpr int BCH = BN_ / 16;             // B-tile wave-chunks
  __shared__ unsigned short L[3 * BUFE];

  const int tidx = threadIdx.x;
  const int wid = tidx >> 6, lane = tidx & 63;
  constexpr int WN = NW / 2;
  const int wm = wid / WN, wn = wid % WN;
  const int lr = lane & 15, lg4 = lane >> 4;

  // bijective XCD swizzle (nwg % 8 == 0 for both grids)
  int wg = blockIdx.y * gridDim.x + blockIdx.x;
  int nwg = gridDim.x * gridDim.y;
  int swz = (wg & 7) * (nwg >> 3) + (wg >> 3);
  const int tm = (swz / gridDim.x) * 128, tn = (swz % gridDim.x) * BN_;

  f32x4 acc[4][4];
#pragma unroll
  for (int m = 0; m < 4; ++m)
#pragma unroll
    for (int n = 0; n < 4; ++n) acc[m][n] = (f32x4)0.0f;

  // prologue: 2 tiles in flight
  stage32<NW, 8>(A, L, tm, 0, tidx);
  stage32<NW, BCH>(Bw, L + AT32, tn, 0, tidx);
  stage32<NW, 8>(A, L + BUFE, tm, GBK, tidx);
  stage32<NW, BCH>(Bw, L + BUFE + AT32, tn, GBK, tidx);
  if constexpr (EPI == 0) asm volatile("s_waitcnt vmcnt(3)" ::: "memory");
  else                    asm volatile("s_waitcnt vmcnt(4)" ::: "memory");
  __builtin_amdgcn_s_barrier();

  for (int i = 0; i < NKT; ++i) {
    unsigned short* cb = L + (i % 3) * BUFE;
    unsigned short* nb = L + ((i + 2) % 3) * BUFE;
    const bool pf = (i + 2 < NKT);

    bf16x8 a[4], b[4];
#pragma unroll
    for (int m = 0; m < 4; ++m)
      a[m] = frag_ld32(cb, wm * 64 + m * 16 + lr, lg4);
#pragma unroll
    for (int n = 0; n < 4; ++n)
      b[n] = frag_ld32(cb + AT32, wn * 64 + n * 16 + lr, lg4);

    if (pf) {
      stage32<NW, 8>(A, nb, tm, (i + 2) * GBK, tidx);
      stage32<NW, BCH>(Bw, nb + AT32, tn, (i + 2) * GBK, tidx);
    }

    asm volatile("s_waitcnt lgkmcnt(0)" ::: "memory");
    __builtin_amdgcn_s_setprio(1);
#pragma unroll
    for (int m = 0; m < 4; ++m)
#pragma unroll
      for (int n = 0; n < 4; ++n)
        acc[m][n] = __builtin_amdgcn_mfma_f32_16x16x32_bf16(a[m], b[n], acc[m][n], 0, 0, 0);
    __builtin_amdgcn_s_setprio(0);

    if (pf) {
      if constexpr (EPI == 0) asm volatile("s_waitcnt vmcnt(3)" ::: "memory");
      else                    asm volatile("s_waitcnt vmcnt(4)" ::: "memory");
    } else {
      asm volatile("s_waitcnt vmcnt(0)" ::: "memory");
    }
    __builtin_amdgcn_s_barrier();
  }

  // epilogue
  if (EPI == 1) {
    float* o = (float*)out;
#pragma unroll
    for (int m = 0; m < 4; ++m) {
      int row0 = tm + wm * 64 + m * 16 + lg4 * 4;
#pragma unroll
      for (int n = 0; n < 4; ++n) {
        int col = tn + wn * 64 + n * 16 + lr;
        float bc = b0[col];
#pragma unroll
        for (int jj = 0; jj < 4; ++jj)
          o[(size_t)(row0 + jj) * DM + col] = acc[m][n][jj] + bc;
      }
    }
  } else {
    const int sel = tn >> 10;                 // block-uniform (1024 % 256 == 0)
    const float* bias = sel == 0 ? b0 : sel == 1 ? b1 : b2;
    const float scl = sel == 0 ? qscale : 1.0f;
    unsigned short* dst = (unsigned short*)out + (size_t)sel * (8u << 20);
    unsigned short* C = L;                    // reuse staging LDS (73.7KB)
    const int bb = tm >> 11, l0 = tm & 2047;
    const int tnl = tn & 1023;

    if (sel < 2) {
      // row-major repack, row stride 264 elems (528B, 16B-aligned)
#pragma unroll
      for (int m = 0; m < 4; ++m) {
        int row0 = wm * 64 + m * 16 + lg4 * 4;
#pragma unroll
        for (int n = 0; n < 4; ++n) {
          int col = wn * 64 + n * 16 + lr;
          float bc = bias[tnl + col];
#pragma unroll
          for (int jj = 0; jj < 4; ++jj)
            C[(row0 + jj) * 264 + col] = f2bf((acc[m][n][jj] + bc) * scl);
        }
      }
      __syncthreads();
#pragma unroll
      for (int j = 0; j < 8; ++j) {
        int c = j * 512 + tidx;               // 0..4095 chunks of 8
        int ll = c >> 5, colc = (c & 31) * 8;
        bf16x8 v = *(const bf16x8*)&C[ll * 264 + colc];
        int c10 = tnl + colc;
        int h = c10 >> 6, dd = c10 & 63;
        *(bf16x8*)&dst[(((size_t)bb * NH + h) * L_SEQ + (l0 + ll)) * DK + dd] = v;
      }
    } else {
      // V: dd-major (pre-transposed) repack, row stride 136 elems (272B)
#pragma unroll
      for (int m = 0; m < 4; ++m) {
        int row0 = wm * 64 + m * 16 + lg4 * 4;
#pragma unroll
        for (int n = 0; n < 4; ++n) {
          int col = wn * 64 + n * 16 + lr;
          float bc = bias[tnl + col];
          ushort4 pk;
          pk.x = f2bf(acc[m][n][0] + bc);
          pk.y = f2bf(acc[m][n][1] + bc);
          pk.z = f2bf(acc[m][n][2] + bc);
          pk.w = f2bf(acc[m][n][3] + bc);
          *(ushort4*)&C[col * 136 + row0] = pk;
        }
      }
      __syncthreads();
#pragma unroll
      for (int j = 0; j < 8; ++j) {
        int c = j * 512 + tidx;
        int ddl = c >> 4, tk = (c & 15) * 8;
        bf16x8 v = *(const bf16x8*)&C[ddl * 136 + tk];
        int c10 = tnl + ddl;
        int h = c10 >> 6, dd = c10 & 63;
        *(bf16x8*)&dst[(((size_t)bb * NH + h) * DK + dd) * L_SEQ + (l0 + tk)] = v;
      }
    }
  }
}

// ---------------- flash attention: swapped 32x32, FIXED-MAX softmax -------
// (frozen from R12)
#define KVB 64
#define LDK 68
#define NTILE (L_SEQ / KVB)
#define FIXM  32.0f
#define CLO  (-144.269504f - FIXM)
#define CHI  (144.269504f - FIXM)

__device__ __forceinline__ bf16x8 lds_frag(const unsigned short* p) {
  uint2 a = *(const uint2*)p;
  uint2 b = *(const uint2*)(p + 4);
  u32x4 t = {a.x, a.y, b.x, b.y};
  return __builtin_bit_cast(bf16x8, t);
}

__device__ __forceinline__ void lds_st16(unsigned short* p, uint4 v) {
  *(uint2*)p = make_uint2(v.x, v.y);
  *(uint2*)(p + 4) = make_uint2(v.z, v.w);
}

__device__ __forceinline__ unsigned cvtpk(float a, float b) {
  unsigned r;
  asm("v_cvt_pk_bf16_f32 %0, %1, %2" : "=v"(r) : "v"(a), "v"(b));
  return r;
}

__device__ __forceinline__ void pl32swap(unsigned& a, unsigned& b) {
  unsigned sa = (unsigned)__shfl_xor((int)a, 32);
  unsigned sb = (unsigned)__shfl_xor((int)b, 32);
  int hi = (threadIdx.x & 63) >> 5;
  unsigned na = hi ? sb : a;
  unsigned nb = hi ? b : sa;
  a = na; b = nb;
}

__device__ __forceinline__ void xpair32(float x, float& lo, float& hi2) {
  unsigned a = __builtin_bit_cast(unsigned, x), b = a;
  pl32swap(a, b);
  lo = __builtin_bit_cast(float, a);
  hi2 = __builtin_bit_cast(float, b);
}

#define MFMA32(a, b, c) __builtin_amdgcn_mfma_f32_32x32x16_bf16(a, b, c, 0, 0, 0)

__global__ __launch_bounds__(256, 4) void flash_attn(
    const unsigned short* __restrict__ Qg,
    const unsigned short* __restrict__ Kg,
    const unsigned short* __restrict__ VTg,
    unsigned short* __restrict__ ctx) {
  __shared__ unsigned short Ks[2][64 * LDK];
  __shared__ unsigned short Vs[2][64 * LDK];

  const int bh = blockIdx.x, b = bh >> 4, h = bh & 15;
  const int q0 = blockIdx.y * 128;
  const int tid = threadIdx.x;
  const int w = tid >> 6, lane = tid & 63;
  const int l31 = lane & 31, hi = lane >> 5;
  const size_t head = (size_t)bh * (L_SEQ * DK);

  const int srow = w * 16 + (lane >> 2);
  const int scol = (lane & 3) * 16;

  bf16x8 qf[4];
  {
    const unsigned short* qp = Qg + head + (size_t)(q0 + w * 32 + l31) * DK + hi * 8;
#pragma unroll
    for (int ks = 0; ks < 4; ++ks) qf[ks] = *(const bf16x8*)(qp + ks * 16);
  }

  f32x16 o[2];
  o[0] = (f32x16)0.0f; o[1] = (f32x16)0.0f;
  float lq = 0.0f;

  {
    const unsigned short* kp = Kg + head + (size_t)srow * DK + scol;
    uint4 k0 = *(const uint4*)kp, k1 = *(const uint4*)(kp + 8);
    const unsigned short* vp = VTg + head + (size_t)srow * L_SEQ + scol;
    uint4 v0 = *(const uint4*)vp, v1 = *(const uint4*)(vp + 8);
    lds_st16(Ks[0] + srow * LDK + scol, k0);
    lds_st16(Ks[0] + srow * LDK + scol + 8, k1);
    lds_st16(Vs[0] + srow * LDK + scol, v0);
    lds_st16(Vs[0] + srow * LDK + scol + 8, v1);
  }
  __syncthreads();

  int cur = 0;
  for (int t = 0; t < NTILE; ++t) {
    uint4 kr0, kr1, vr0, vr1;
    const int kv0n = (t + 1) * KVB;
    if (t + 1 < NTILE) {
      const unsigned short* kp = Kg + head + (size_t)(kv0n + srow) * DK + scol;
      kr0 = *(const uint4*)kp; kr1 = *(const uint4*)(kp + 8);
    }

    f32x16 s0 = (f32x16)(-FIXM), s1 = (f32x16)(-FIXM);
#pragma unroll
    for (int ks = 0; ks < 4; ++ks) {
      bf16x8 k0 = lds_frag(Ks[cur] + l31 * LDK + ks * 16 + hi * 8);
      s0 = MFMA32(k0, qf[ks], s0);
      bf16x8 k1 = lds_frag(Ks[cur] + (32 + l31) * LDK + ks * 16 + hi * 8);
      s1 = MFMA32(k1, qf[ks], s1);
    }

#pragma unroll
    for (int r = 0; r < 16; ++r) {
      s0[r] = EXP2F(__builtin_amdgcn_fmed3f(s0[r], CLO, CHI));
      s1[r] = EXP2F(__builtin_amdgcn_fmed3f(s1[r], CLO, CHI));
    }
    {
      float l4[4];
#pragma unroll
      for (int r = 0; r < 4; ++r)
        l4[r] = ((s0[r] + s0[r + 4]) + (s0[r + 8] + s0[r + 12]))
              + ((s1[r] + s1[r + 4]) + (s1[r + 8] + s1[r + 12]));
      float ls = (l4[0] + l4[1]) + (l4[2] + l4[3]);
      float a, c; xpair32(ls, a, c);
      lq += a + c;
    }

    bf16x8 pa[4];
#pragma unroll
    for (int ks = 0; ks < 4; ++ks) {
      const int s8 = (ks & 1) * 8;
      const f32x16 sv = (ks < 2) ? s0 : s1;
      unsigned uA0 = cvtpk(sv[s8 + 0], sv[s8 + 1]);
      unsigned uA1 = cvtpk(sv[s8 + 2], sv[s8 + 3]);
      unsigned uB0 = cvtpk(sv[s8 + 4], sv[s8 + 5]);
      unsigned uB1 = cvtpk(sv[s8 + 6], sv[s8 + 7]);
      pl32swap(uA0, uB0);
      pl32swap(uA1, uB1);
      u32x4 tt = {uA0, uA1, uB0, uB1};
      pa[ks] = __builtin_bit_cast(bf16x8, tt);
    }

    if (t + 1 < NTILE) {
      const unsigned short* vp = VTg + head + (size_t)srow * L_SEQ + kv0n + scol;
      vr0 = *(const uint4*)vp; vr1 = *(const uint4*)(vp + 8);
    }

#pragma unroll
    for (int jb = 0; jb < 2; ++jb)
#pragma unroll
      for (int ks = 0; ks < 4; ++ks) {
        bf16x8 vf = lds_frag(Vs[cur] + (32 * jb + l31) * LDK + ks * 16 + hi * 8);
        o[jb] = MFMA32(vf, pa[ks], o[jb]);
      }

    if (t + 1 < NTILE) {
      lds_st16(Ks[cur ^ 1] + srow * LDK + scol, kr0);
      lds_st16(Ks[cur ^ 1] + srow * LDK + scol + 8, kr1);
      lds_st16(Vs[cur ^ 1] + srow * LDK + scol, vr0);
      lds_st16(Vs[cur ^ 1] + srow * LDK + scol + 8, vr1);
    }
    __syncthreads();
    cur ^= 1;
  }

  {
    float inv = 1.0f / lq;
    const int tok = q0 + w * 32 + l31;
    size_t base = ((size_t)b * L_SEQ + tok) * DM + h * DK;
#pragma unroll
    for (int jb = 0; jb < 2; ++jb)
#pragma unroll
      for (int c = 0; c < 4; ++c) {
        ushort4 pk;
        pk.x = f2bf(o[jb][4 * c + 0] * inv);
        pk.y = f2bf(o[jb][4 * c + 1] * inv);
        pk.z = f2bf(o[jb][4 * c + 2] * inv);
        pk.w = f2bf(o[jb][4 * c + 3] * inv);
        *(ushort4*)&ctx[base + jb * 32 + c * 8 + hi * 4] = pk;
      }
  }
}

// ---------------- launch ----------------
extern "C" void kernel_launch(void* const* d_in, const int* in_sizes, int n_in,
                              void* d_out, int out_size, void* d_ws, size_t ws_size,
                              hipStream_t stream) {
  (void)in_sizes; (void)n_in; (void)out_size; (void)ws_size;
  const float* x  = (const float*)d_in[0];
  const float* Wq = (const float*)d_in[1];
  const float* bq = (const float*)d_in[2];
  const float* Wk = (const float*)d_in[3];
  const float* bk = (const float*)d_in[4];
  const float* Wv = (const float*)d_in[5];
  const float* bv = (const float*)d_in[6];
  const float* Wo = (const float*)d_in[7];
  const float* bo = (const float*)d_in[8];

  char* ws = (char*)d_ws;
  unsigned short* xb  = (unsigned short*)(ws);                    // 16 MB
  unsigned short* wqb = (unsigned short*)(ws + (16ull << 20));    // wq|wk|wv|wo contiguous
  unsigned short* wob = (unsigned short*)(ws + (22ull << 20));
  unsigned short* Qb  = (unsigned short*)(ws + (24ull << 20));    // Q|K|VT, 16MB apart
  unsigned short* Kb  = (unsigned short*)(ws + (40ull << 20));
  unsigned short* VTb = (unsigned short*)(ws + (56ull << 20));
  unsigned short* ctx = xb;

  cvt_f32_bf16<<<2048, 256, 0, stream>>>(x, xb, M_TOK * DM / 4);
  cvt_w4<<<4096, 256, 0, stream>>>(Wq, Wk, Wv, Wo, wqb);

  // Fused QKV projection (BK=32, 2 blocks/CU); Q scaled by 0.125*log2(e)
  gemm8<0, 256, 8><<<dim3(3 * DM / 256, M_TOK / 128), 512, 0, stream>>>(
      xb, wqb, bq, bk, bv, 0.1803368801f, Qb);

  dim3 ga(BATCH * NH, L_SEQ / 128);
  flash_attn<<<ga, 256, 0, stream>>>(Qb, Kb, VTb, ctx);

  gemm8<1, 128, 4><<<dim3(DM / 128, M_TOK / 128), 256, 0, stream>>>(
      ctx, wob, bo, nullptr, nullptr, 1.0f, d_out);
}